// Round 3
// baseline (127997.241 us; speedup 1.0000x reference)
//
#include <hip/hip_runtime.h>
#include <math.h>

#define Bb 8
#define Tt 168
#define Nn 512
#define Cc 32
#define Ll 4
#define Kk 50
#define NCH 4
#define BPC 2                     // batches per chunk (chunk boundary = t==0, no cross-chunk reads)
#define BTc (BPC*Tt)              // 336
#define BTNc ((size_t)BTc*Nn)
#define BTCNc ((size_t)BTc*Cc*Nn)
#define BT (Bb*Tt)
#define BTN ((size_t)Bb*Tt*Nn)
#define BTCN ((size_t)Bb*Tt*Cc*Nn)
#define GB 16                     // GRU blocks (n-sliced), all co-resident

__device__ __forceinline__ float sigm(float v) { return 1.0f/(1.0f + expf(-v)); }

// ---------------- weight transpose for GRU ----------------
__global__ void k_wt(const float* __restrict__ zl, const float* __restrict__ rl,
                     const float* __restrict__ hl,
                     float* __restrict__ zT, float* __restrict__ rT,
                     float* __restrict__ hxT, float* __restrict__ hhT) {
  int idx = blockIdx.x*256 + threadIdx.x;
  if (idx >= Nn*1024) return;
  int n = idx >> 10, j = idx & 1023;
  zT[j*Nn + n] = zl[idx];
  rT[j*Nn + n] = rl[idx];
  float hv = hl[idx];
  if (j < Nn) hxT[j*Nn + n] = hv;
  else        hhT[(j-Nn)*Nn + n] = hv;
}

// ---------------- adaptive adjacency: softmax(relu(nv1@nv2), axis=1) ----------------
__global__ void k_adp(const float* __restrict__ nv1, const float* __restrict__ nv2,
                      float* __restrict__ adp) {
  int i = blockIdx.x;
  __shared__ float row[512];
  __shared__ float red[256];
  float v1[10];
  #pragma unroll
  for (int k=0;k<10;k++) v1[k] = nv1[i*10+k];
  for (int jj = threadIdx.x; jj < 512; jj += 256) {
    float s = 0.f;
    #pragma unroll
    for (int k=0;k<10;k++) s += v1[k]*nv2[k*Nn + jj];
    row[jj] = fmaxf(s, 0.f);
  }
  __syncthreads();
  float m = fmaxf(row[threadIdx.x], row[threadIdx.x+256]);
  red[threadIdx.x] = m; __syncthreads();
  for (int s=128; s>0; s>>=1) { if (threadIdx.x < s) red[threadIdx.x] = fmaxf(red[threadIdx.x], red[threadIdx.x+s]); __syncthreads(); }
  float mx = red[0]; __syncthreads();
  float e0 = expf(row[threadIdx.x]      - mx);
  float e1 = expf(row[threadIdx.x+256]  - mx);
  red[threadIdx.x] = e0 + e1; __syncthreads();
  for (int s=128; s>0; s>>=1) { if (threadIdx.x < s) red[threadIdx.x] += red[threadIdx.x+s]; __syncthreads(); }
  float inv = 1.f/red[0];
  adp[(size_t)i*Nn + threadIdx.x]       = e0*inv;
  adp[(size_t)i*Nn + threadIdx.x + 256] = e1*inv;
}

// ---------------- input transform: x = conv1x1(input[[0,3,5,6]]) -> (B,T,C,N) ----------------
__global__ void k_intransform(const float* __restrict__ input, const float* __restrict__ skw,
                              const float* __restrict__ skb, float* __restrict__ x) {
  size_t idx = (size_t)blockIdx.x*256 + threadIdx.x;
  if (idx >= BTN) return;
  int n = idx & 511;
  size_t bt = idx >> 9;
  int b = (int)(bt / Tt), t = (int)(bt % Tt);
  size_t chs = (size_t)Tt*Nn;
  size_t base = (((size_t)b*7)*Tt + t)*Nn + n;
  float v0 = input[base + 0*chs];
  float v3 = input[base + 3*chs];
  float v5 = input[base + 5*chs];
  float v6 = input[base + 6*chs];
  float* xp = x + bt*Cc*Nn + n;
  #pragma unroll
  for (int c=0;c<32;c++)
    xp[(size_t)c*Nn] = skb[c] + skw[c*4+0]*v0 + skw[c*4+1]*v3 + skw[c*4+2]*v5 + skw[c*4+3]*v6;
}

// ---------------- fused filter/gate conv1x2 -> xg_q ; gout_q = W0@xg + bias (chunk-local) ----------------
__launch_bounds__(256)
__global__ void k_fgconv(const float* __restrict__ x, const float* __restrict__ fw,
                         const float* __restrict__ fb, const float* __restrict__ gw,
                         const float* __restrict__ gb, const float* __restrict__ gcwl,
                         const float* __restrict__ gcb,
                         float* __restrict__ xg, float* __restrict__ gout, int chunk) {
  __shared__ float sfw[2048], sgw[2048], sw0[1024], sfb[32], sgb[32], sgcb[32];
  for (int l = threadIdx.x; l < 2048; l += 256) { sfw[l] = fw[l]; sgw[l] = gw[l]; }
  for (int l = threadIdx.x; l < 1024; l += 256) sw0[l] = gcwl[(l>>5)*224 + (l&31)];
  if (threadIdx.x < 32) {
    sfb[threadIdx.x] = fb[threadIdx.x];
    sgb[threadIdx.x] = gb[threadIdx.x];
    sgcb[threadIdx.x] = gcb[threadIdx.x];
  }
  __syncthreads();
  size_t idx = (size_t)blockIdx.x*256 + threadIdx.x;
  if (idx >= BTNc) return;
  int n = idx & 511;
  size_t btl = idx >> 9;
  int t = (int)(btl % Tt);
  size_t btg = (size_t)chunk*BTc + btl;
  const float* xp = x + btg*Cc*Nn + n;
  float xl[32], xr[32];
  #pragma unroll
  for (int c=0;c<32;c++) xr[c] = xp[(size_t)c*Nn];
  if (t == 0) {
    #pragma unroll
    for (int c=0;c<32;c++) xl[c] = 0.f;
  } else {
    const float* xq = xp - (size_t)Cc*Nn;
    #pragma unroll
    for (int c=0;c<32;c++) xl[c] = xq[(size_t)c*Nn];
  }
  float xgv[32];
  for (int c=0;c<32;c++) {
    float f = sfb[c], g = sgb[c];
    #pragma unroll
    for (int cp=0;cp<32;cp++) {
      f += xl[cp]*sfw[(c*32+cp)*2] + xr[cp]*sfw[(c*32+cp)*2+1];
      g += xl[cp]*sgw[(c*32+cp)*2] + xr[cp]*sgw[(c*32+cp)*2+1];
    }
    xgv[c] = tanhf(f) * sigm(g);
  }
  float* xgp = xg + btl*Cc*Nn + n;
  #pragma unroll
  for (int c=0;c<32;c++) xgp[(size_t)c*Nn] = xgv[c];
  float* gp = gout + btl*Cc*Nn + n;
  for (int o=0;o<32;o++) {
    float s = sgcb[o];
    #pragma unroll
    for (int c=0;c<32;c++) s += sw0[o*32+c]*xgv[c];
    gp[(size_t)o*Nn] = s;
  }
}

// ---------------- support GEMM (per bt: (32x512)@(512x512)) + gconv-slot epilogue ----------------
__launch_bounds__(256)
__global__ void k_supgemm(const float* __restrict__ X, const float* __restrict__ A,
                          const float* __restrict__ gcw, int pslot,
                          float* __restrict__ Y, float* __restrict__ gout, int storeY) {
  __shared__ float sX[32][33];
  __shared__ float sA[32][128];
  __shared__ float sW[1024];
  int tid = threadIdx.x;
  int bt = blockIdx.x >> 2;
  int n0 = (blockIdx.x & 3) << 7;
  const float* Xp = X + (size_t)bt*Cc*Nn;
  for (int l = tid; l < 1024; l += 256)
    sW[l] = gcw[(l>>5)*224 + pslot*32 + (l&31)];
  int tx = tid & 31, ty = tid >> 5;
  float acc[4][4];
  #pragma unroll
  for (int i=0;i<4;i++) { acc[i][0]=0.f; acc[i][1]=0.f; acc[i][2]=0.f; acc[i][3]=0.f; }
  for (int k0 = 0; k0 < Nn; k0 += 32) {
    {
      int r = tid >> 3, kk = (tid & 7) << 2;
      const float4 v = *reinterpret_cast<const float4*>(Xp + (size_t)r*Nn + k0 + kk);
      sX[r][kk] = v.x; sX[r][kk+1] = v.y; sX[r][kk+2] = v.z; sX[r][kk+3] = v.w;
    }
    #pragma unroll
    for (int i=0;i<4;i++) {
      int l = tid + i*256;
      int r = l >> 5, cg_ = l & 31;
      *reinterpret_cast<float4*>(&sA[r][cg_<<2]) =
        *reinterpret_cast<const float4*>(A + (size_t)(k0+r)*Nn + n0 + (cg_<<2));
    }
    __syncthreads();
    #pragma unroll
    for (int k=0;k<32;k++) {
      float4 bv = *reinterpret_cast<const float4*>(&sA[k][tx<<2]);
      float a0 = sX[(ty<<2)+0][k];
      float a1 = sX[(ty<<2)+1][k];
      float a2 = sX[(ty<<2)+2][k];
      float a3 = sX[(ty<<2)+3][k];
      acc[0][0]+=a0*bv.x; acc[0][1]+=a0*bv.y; acc[0][2]+=a0*bv.z; acc[0][3]+=a0*bv.w;
      acc[1][0]+=a1*bv.x; acc[1][1]+=a1*bv.y; acc[1][2]+=a1*bv.z; acc[1][3]+=a1*bv.w;
      acc[2][0]+=a2*bv.x; acc[2][1]+=a2*bv.y; acc[2][2]+=a2*bv.z; acc[2][3]+=a2*bv.w;
      acc[3][0]+=a3*bv.x; acc[3][1]+=a3*bv.y; acc[3][2]+=a3*bv.z; acc[3][3]+=a3*bv.w;
    }
    __syncthreads();
  }
  if (storeY) {
    float* Yp = Y + (size_t)bt*Cc*Nn + n0 + (tx<<2);
    #pragma unroll
    for (int i=0;i<4;i++)
      *reinterpret_cast<float4*>(Yp + (size_t)((ty<<2)+i)*Nn) =
        make_float4(acc[i][0],acc[i][1],acc[i][2],acc[i][3]);
  }
  #pragma unroll
  for (int i=0;i<4;i++)
    *reinterpret_cast<float4*>(&sA[(ty<<2)+i][tx<<2]) =
      make_float4(acc[i][0],acc[i][1],acc[i][2],acc[i][3]);
  __syncthreads();
  float og[4][4];
  #pragma unroll
  for (int i=0;i<4;i++) { og[i][0]=0.f; og[i][1]=0.f; og[i][2]=0.f; og[i][3]=0.f; }
  #pragma unroll 8
  for (int c=0;c<32;c++) {
    float4 yv = *reinterpret_cast<const float4*>(&sA[c][tx<<2]);
    float w0 = sW[((ty<<2)+0)*32 + c];
    float w1 = sW[((ty<<2)+1)*32 + c];
    float w2 = sW[((ty<<2)+2)*32 + c];
    float w3 = sW[((ty<<2)+3)*32 + c];
    og[0][0]+=w0*yv.x; og[0][1]+=w0*yv.y; og[0][2]+=w0*yv.z; og[0][3]+=w0*yv.w;
    og[1][0]+=w1*yv.x; og[1][1]+=w1*yv.y; og[1][2]+=w1*yv.z; og[1][3]+=w1*yv.w;
    og[2][0]+=w2*yv.x; og[2][1]+=w2*yv.y; og[2][2]+=w2*yv.z; og[2][3]+=w2*yv.w;
    og[3][0]+=w3*yv.x; og[3][1]+=w3*yv.y; og[3][2]+=w3*yv.z; og[3][3]+=w3*yv.w;
  }
  float* gp = gout + (size_t)bt*Cc*Nn + n0 + (tx<<2);
  #pragma unroll
  for (int i=0;i<4;i++) {
    float4 cur = *reinterpret_cast<float4*>(gp + (size_t)((ty<<2)+i)*Nn);
    cur.x += og[i][0]; cur.y += og[i][1]; cur.z += og[i][2]; cur.w += og[i][3];
    *reinterpret_cast<float4*>(gp + (size_t)((ty<<2)+i)*Nn) = cur;
  }
}

// ---------------- skip gather: skipK[b,k,c,t] (+)= xg_q[btl,c,node] ----------------
__global__ void k_skipgather(const float* __restrict__ xg, const int* __restrict__ miss,
                             float* __restrict__ skipK, int chunk, int first) {
  int idx = blockIdx.x*256 + threadIdx.x;
  if (idx >= BPC*Kk*Tt) return;
  int t = idx % Tt;
  int k = (idx / Tt) % Kk;
  int bloc = idx / (Tt*Kk);
  int bg = chunk*BPC + bloc;
  int node = miss[bg*Kk + k];
  const float* xp = xg + (((size_t)bloc*Tt + t)*Cc)*Nn + node;
  float* sp = skipK + (((size_t)bg*Kk + k)*Cc)*Tt + t;
  #pragma unroll
  for (int c=0;c<32;c++) {
    float v = xp[(size_t)c*Nn];
    sp[(size_t)c*Tt] = first ? v : (sp[(size_t)c*Tt] + v);
  }
}

// ---------------- ingru: Xs[t,b,n] = sum_c gout_q*iw + ib ----------------
__global__ void k_ingru(const float* __restrict__ gout, const float* __restrict__ iw,
                        const float* __restrict__ ib2, float* __restrict__ Xs, int chunk) {
  size_t idx = (size_t)blockIdx.x*256 + threadIdx.x;
  if (idx >= BTNc) return;
  int n = idx & 511;
  size_t btl = idx >> 9;
  int b = chunk*BPC + (int)(btl / Tt), t = (int)(btl % Tt);
  const float* gp = gout + btl*Cc*Nn + n;
  float s = ib2[0];
  #pragma unroll
  for (int c=0;c<Cc;c++) s += iw[c]*gp[(size_t)c*Nn];
  Xs[((size_t)t*Bb + b)*Nn + n] = s;
}

// ---------------- x += gout_q (chunk fold) ----------------
__global__ void k_xfold(float* __restrict__ x, const float* __restrict__ gout, int chunk) {
  size_t idx = (size_t)blockIdx.x*256 + threadIdx.x;
  if (idx >= BTCNc) return;
  x[(size_t)chunk*BTCNc + idx] += gout[idx];
}

// ---------------- GRU: 16 n-sliced blocks, custom monotone atomic barrier ----------------
__device__ __forceinline__ void gbar(int* cnt, int target) {
  __syncthreads();
  if (threadIdx.x == 0) {
    __threadfence();                         // release: prior global writes visible
    atomicAdd(cnt, 1);
    while (atomicAdd(cnt, 0) < target) { __builtin_amdgcn_s_sleep(16); }
    __threadfence();                         // acquire: see peers' writes
  }
  __syncthreads();
}

__launch_bounds__(1024)
__global__ void k_gru2(const float* __restrict__ Xs, const float* __restrict__ input,
                       const float* __restrict__ zT, const float* __restrict__ rT,
                       const float* __restrict__ hxT, const float* __restrict__ hhT,
                       const float* __restrict__ zb, const float* __restrict__ rb,
                       const float* __restrict__ hb,
                       float* __restrict__ h_g, float* __restrict__ xin_g,
                       float* __restrict__ rh_g, float* __restrict__ outs,
                       int* cnt) {
  __shared__ float xh[8][1024];   // [b][ xin(0:512) | h(512:1024) ]
  __shared__ float rhl[8][512];
  const int tid = threadIdx.x;
  const int b  = tid >> 7;          // wave-uniform (b changes every 2 waves)
  const int np = (tid >> 3) & 15;   // n-pair index
  const int kq = tid & 7;           // K interleave (mod 8)
  const int n0 = blockIdx.x * 32;
  const int n  = n0 + np*2;

  // t=0 init: h=0, xin = sigm(Xs[0]*Mi)
  if (kq == 0) {
    #pragma unroll
    for (int e=0;e<2;e++) {
      int nn = n + e;
      float Xi = Xs[(size_t)b*Nn + nn];
      float Mi = input[(((size_t)b*7+1)*Tt + 0)*Nn + nn];
      h_g[b*Nn + nn] = 0.f;
      xin_g[b*Nn + nn] = sigm(Xi*Mi);
    }
  }
  int bar = 1;
  gbar(cnt, (bar++)*GB);

  const float* Wz = zT  + n;
  const float* Wr = rT  + n;
  const float* Wx = hxT + n;
  const float* Wh = hhT + n;
  const float zbv0 = zb[n], zbv1 = zb[n+1];
  const float rbv0 = rb[n], rbv1 = rb[n+1];
  const float hbv0 = hb[n], hbv1 = hb[n+1];

  for (int t = 0; t < Tt; t++) {
    // stage xin,h -> LDS (coalesced, 8 floats/thread)
    {
      int o = tid << 3;
      int rb_ = o >> 10, cb = o & 1023;
      const float* src = (cb < 512) ? (xin_g + rb_*Nn + cb) : (h_g + rb_*Nn + (cb - 512));
      float4 v0 = *reinterpret_cast<const float4*>(src);
      float4 v1 = *reinterpret_cast<const float4*>(src + 4);
      *reinterpret_cast<float4*>(&xh[rb_][cb])     = v0;
      *reinterpret_cast<float4*>(&xh[rb_][cb + 4]) = v1;
    }
    __syncthreads();
    // ---- phase A: z, r (K=1024), hx (K=512), K interleaved mod 8 ----
    float az0=0,az1=0,ar0=0,ar1=0;
    #pragma unroll 4
    for (int i=0;i<128;i++) {
      int j = (i<<3) + kq;
      float xv = xh[b][j];
      float2 wz = *reinterpret_cast<const float2*>(Wz + (size_t)j*Nn);
      float2 wr = *reinterpret_cast<const float2*>(Wr + (size_t)j*Nn);
      az0 += xv*wz.x; az1 += xv*wz.y;
      ar0 += xv*wr.x; ar1 += xv*wr.y;
    }
    float ah0=0, ah1=0;
    #pragma unroll 4
    for (int i=0;i<64;i++) {
      int j = (i<<3) + kq;
      float xv = xh[b][j];
      float2 wx = *reinterpret_cast<const float2*>(Wx + (size_t)j*Nn);
      ah0 += xv*wx.x; ah1 += xv*wx.y;
    }
    #pragma unroll
    for (int d=1; d<8; d<<=1) {
      az0 += __shfl_xor(az0, d); az1 += __shfl_xor(az1, d);
      ar0 += __shfl_xor(ar0, d); ar1 += __shfl_xor(ar1, d);
      ah0 += __shfl_xor(ah0, d); ah1 += __shfl_xor(ah1, d);
    }
    float z0=0.f, z1=0.f, hx0=0.f, hx1=0.f;
    if (kq == 0) {
      z0 = sigm(az0 + zbv0); z1 = sigm(az1 + zbv1);
      hx0 = ah0; hx1 = ah1;
      float r0 = sigm(ar0 + rbv0), r1 = sigm(ar1 + rbv1);
      float h0v = xh[b][512+n], h1v = xh[b][512+n+1];
      *reinterpret_cast<float2*>(rh_g + b*Nn + n) = make_float2(r0*h0v, r1*h1v);
    }
    gbar(cnt, (bar++)*GB);
    // stage rh -> LDS
    {
      int o = tid << 2;
      int rb_ = o >> 9, cb = o & 511;
      *reinterpret_cast<float4*>(&rhl[rb_][cb]) =
        *reinterpret_cast<const float4*>(rh_g + rb_*Nn + cb);
    }
    __syncthreads();
    // ---- phase B: hh (K=512) + combine ----
    float hh0=0, hh1=0;
    #pragma unroll 4
    for (int i=0;i<64;i++) {
      int m = (i<<3) + kq;
      float rv = rhl[b][m];
      float2 wh = *reinterpret_cast<const float2*>(Wh + (size_t)m*Nn);
      hh0 += rv*wh.x; hh1 += rv*wh.y;
    }
    #pragma unroll
    for (int d=1; d<8; d<<=1) { hh0 += __shfl_xor(hh0,d); hh1 += __shfl_xor(hh1,d); }
    if (kq == 0) {
      float h0v = xh[b][512+n], h1v = xh[b][512+n+1];
      float ht0 = tanhf(hx0 + hh0 + hbv0);
      float ht1 = tanhf(hx1 + hh1 + hbv1);
      float hn0 = (1.f - z0)*h0v + z0*ht0;
      float hn1 = (1.f - z1)*h1v + z1*ht1;
      *reinterpret_cast<float2*>(h_g + b*Nn + n) = make_float2(hn0, hn1);
      *reinterpret_cast<float2*>(outs + ((size_t)t*Bb + b)*Nn + n) = make_float2(hn0, hn1);
      if (t+1 < Tt) {
        float Xi0 = Xs[((size_t)(t+1)*Bb + b)*Nn + n];
        float Xi1 = Xs[((size_t)(t+1)*Bb + b)*Nn + n + 1];
        float Mi0 = input[(((size_t)b*7+1)*Tt + (t+1))*Nn + n];
        float Mi1 = input[(((size_t)b*7+1)*Tt + (t+1))*Nn + n + 1];
        xin_g[b*Nn+n]   = sigm(Xi0*Mi0 + hn0*(1.f - Mi0));
        xin_g[b*Nn+n+1] = sigm(Xi1*Mi1 + hn1*(1.f - Mi1));
      }
    }
    gbar(cnt, (bar++)*GB);
  }
}

// ---------------- x += outs*rw + rb (after GRU) ----------------
__global__ void k_xre(float* __restrict__ x, const float* __restrict__ outs,
                      const float* __restrict__ rw, const float* __restrict__ rb2) {
  size_t idx = (size_t)blockIdx.x*256 + threadIdx.x;
  if (idx >= BTCN) return;
  int n = idx & 511;
  int c = (int)((idx >> 9) & 31);
  size_t bt = idx >> 14;
  int b = (int)(bt / Tt), t = (int)(bt % Tt);
  float o = outs[((size_t)t*Bb + b)*Nn + n];
  x[idx] += o*rw[c] + rb2[c];
}

// ---------------- head: relu(skipK) -> end1 relu -> end2 ----------------
__launch_bounds__(256)
__global__ void k_head(const float* __restrict__ skipK,
                       const float* __restrict__ e1w, const float* __restrict__ e1b,
                       const float* __restrict__ e2w, const float* __restrict__ e2b,
                       float* __restrict__ out) {
  __shared__ float sw[2048], sb[64], s2[64];
  for (int l = threadIdx.x; l < 2048; l += 256) sw[l] = e1w[l];
  if (threadIdx.x < 64) { sb[threadIdx.x] = e1b[threadIdx.x]; s2[threadIdx.x] = e2w[threadIdx.x]; }
  __syncthreads();
  int idx = blockIdx.x*256 + threadIdx.x;
  if (idx >= Bb*Kk*Tt) return;
  int t = idx % Tt;
  int k = (idx / Tt) % Kk;
  int b = idx / (Tt*Kk);
  const float* sp = skipK + (((size_t)b*Kk + k)*Cc)*Tt + t;
  float in[32];
  #pragma unroll
  for (int c=0;c<32;c++) in[c] = fmaxf(sp[(size_t)c*Tt], 0.f);
  float acc = e2b[0];
  for (int o=0;o<64;o++) {
    float s = sb[o];
    #pragma unroll
    for (int c=0;c<32;c++) s += sw[o*32+c]*in[c];
    acc += s2[o]*fmaxf(s, 0.f);
  }
  out[idx] = acc;
}

extern "C" void kernel_launch(void* const* d_in, const int* in_sizes, int n_in,
                              void* d_out, int out_size, void* d_ws, size_t ws_size,
                              hipStream_t stream) {
  const float* input = (const float*)d_in[0];
  const int*   miss  = (const int*)  d_in[1];
  const float* sup0  = (const float*)d_in[2];
  const float* sup1  = (const float*)d_in[3];
  const float* nv1   = (const float*)d_in[4];
  const float* nv2   = (const float*)d_in[5];
  const float* skw   = (const float*)d_in[6];
  const float* skb   = (const float*)d_in[7];
  const float* fw    = (const float*)d_in[8];
  const float* fb    = (const float*)d_in[9];
  const float* gw    = (const float*)d_in[10];
  const float* gb    = (const float*)d_in[11];
  const float* gcw   = (const float*)d_in[12];
  const float* gcb   = (const float*)d_in[13];
  const float* iw    = (const float*)d_in[14];
  const float* ib2   = (const float*)d_in[15];
  const float* rw    = (const float*)d_in[16];
  const float* rb2   = (const float*)d_in[17];
  const float* zl    = (const float*)d_in[18];
  const float* zb    = (const float*)d_in[19];
  const float* rl    = (const float*)d_in[20];
  const float* rb    = (const float*)d_in[21];
  const float* hl    = (const float*)d_in[22];
  const float* hb    = (const float*)d_in[23];
  const float* e1w   = (const float*)d_in[24];
  const float* e1b   = (const float*)d_in[25];
  const float* e2w   = (const float*)d_in[26];
  const float* e2b   = (const float*)d_in[27];
  float* out = (float*)d_out;

  float* p     = (float*)d_ws;
  float* x     = p; p += BTCN;
  float* xg    = p; p += BTCNc;
  float* tmp1  = p; p += BTCNc;
  float* gout  = p; p += BTCNc;
  float* skipK = p; p += (size_t)Bb*Kk*Cc*Tt;
  float* adp   = p; p += (size_t)Nn*Nn;
  float* zT    = p; p += (size_t)1024*Nn;
  float* rT    = p; p += (size_t)1024*Nn;
  float* hxT   = p; p += (size_t)Nn*Nn;
  float* hhT   = p; p += (size_t)Nn*Nn;
  float* Xs    = p; p += (size_t)Tt*Bb*Nn;
  float* outs  = p; p += (size_t)Tt*Bb*Nn;
  float* h_g   = p; p += Bb*Nn;
  float* xin_g = p; p += Bb*Nn;
  float* rh_g  = p; p += Bb*Nn;
  int*   cnt   = (int*)p; p += 16;

  k_wt<<<(Nn*1024 + 255)/256, 256, 0, stream>>>(zl, rl, hl, zT, rT, hxT, hhT);
  k_adp<<<Nn, 256, 0, stream>>>(nv1, nv2, adp);
  k_intransform<<<(int)((BTN + 255)/256), 256, 0, stream>>>(input, skw, skb, x);

  const float* sups[3] = {sup0, sup1, adp};
  for (int layer = 0; layer < Ll; layer++) {
    for (int chunk = 0; chunk < NCH; chunk++) {
      k_fgconv<<<(int)((BTNc + 255)/256), 256, 0, stream>>>(
          x, fw + layer*2048, fb + layer*32, gw + layer*2048, gb + layer*32,
          gcw + layer*32*224, gcb + layer*32, xg, gout, chunk);
      for (int s = 0; s < 3; s++) {
        k_supgemm<<<BTc*4, 256, 0, stream>>>(xg,   sups[s], gcw + layer*32*224, 2*s+1, tmp1, gout, 1);
        k_supgemm<<<BTc*4, 256, 0, stream>>>(tmp1, sups[s], gcw + layer*32*224, 2*s+2, tmp1, gout, 0);
      }
      k_skipgather<<<(BPC*Kk*Tt + 255)/256, 256, 0, stream>>>(xg, miss, skipK, chunk, layer == 0 ? 1 : 0);
      k_ingru<<<(int)((BTNc + 255)/256), 256, 0, stream>>>(gout, iw, ib2, Xs, chunk);
      k_xfold<<<(int)((BTCNc + 255)/256), 256, 0, stream>>>(x, gout, chunk);
    }
    hipMemsetAsync(cnt, 0, sizeof(int), stream);
    k_gru2<<<GB, 1024, 0, stream>>>(Xs, input, zT, rT, hxT, hhT, zb, rb, hb,
                                    h_g, xin_g, rh_g, outs, cnt);
    k_xre<<<(int)((BTCN + 255)/256), 256, 0, stream>>>(x, outs, rw, rb2);
  }
  k_head<<<(Bb*Kk*Tt + 255)/256, 256, 0, stream>>>(skipK, e1w, e1b, e2w, e2b, out);
}

// Round 4
// 44007.721 us; speedup vs baseline: 2.9085x; 2.9085x over previous
//
#include <hip/hip_runtime.h>
#include <math.h>

#define Bb 8
#define Tt 168
#define Nn 512
#define Cc 32
#define Ll 4
#define Kk 50
#define NCH 4
#define BPC 2                     // batches per chunk (chunk boundary = t==0, no cross-chunk reads)
#define BTc (BPC*Tt)              // 336
#define BTNc ((size_t)BTc*Nn)
#define BTCNc ((size_t)BTc*Cc*Nn)
#define BT (Bb*Tt)
#define BTN ((size_t)Bb*Tt*Nn)
#define BTCN ((size_t)Bb*Tt*Cc*Nn)
#define GRU_P 8                   // n-slices per batch (slice = bid%8 -> one XCD per slice)

__device__ __forceinline__ float sigm(float v) { return 1.0f/(1.0f + expf(-v)); }

__device__ __forceinline__ float sysload(const float* p) {
  return __hip_atomic_load(p, __ATOMIC_RELAXED, __HIP_MEMORY_SCOPE_SYSTEM);
}
__device__ __forceinline__ void sysstore(float* p, float v) {
  __hip_atomic_store(p, v, __ATOMIC_RELAXED, __HIP_MEMORY_SCOPE_SYSTEM);
}

// ---------------- weight transpose for GRU ----------------
__global__ void k_wt(const float* __restrict__ zl, const float* __restrict__ rl,
                     const float* __restrict__ hl,
                     float* __restrict__ zT, float* __restrict__ rT,
                     float* __restrict__ hxT, float* __restrict__ hhT) {
  int idx = blockIdx.x*256 + threadIdx.x;
  if (idx >= Nn*1024) return;
  int n = idx >> 10, j = idx & 1023;
  zT[j*Nn + n] = zl[idx];
  rT[j*Nn + n] = rl[idx];
  float hv = hl[idx];
  if (j < Nn) hxT[j*Nn + n] = hv;
  else        hhT[(j-Nn)*Nn + n] = hv;
}

// ---------------- adaptive adjacency: softmax(relu(nv1@nv2), axis=1) ----------------
__global__ void k_adp(const float* __restrict__ nv1, const float* __restrict__ nv2,
                      float* __restrict__ adp) {
  int i = blockIdx.x;
  __shared__ float row[512];
  __shared__ float red[256];
  float v1[10];
  #pragma unroll
  for (int k=0;k<10;k++) v1[k] = nv1[i*10+k];
  for (int jj = threadIdx.x; jj < 512; jj += 256) {
    float s = 0.f;
    #pragma unroll
    for (int k=0;k<10;k++) s += v1[k]*nv2[k*Nn + jj];
    row[jj] = fmaxf(s, 0.f);
  }
  __syncthreads();
  float m = fmaxf(row[threadIdx.x], row[threadIdx.x+256]);
  red[threadIdx.x] = m; __syncthreads();
  for (int s=128; s>0; s>>=1) { if (threadIdx.x < s) red[threadIdx.x] = fmaxf(red[threadIdx.x], red[threadIdx.x+s]); __syncthreads(); }
  float mx = red[0]; __syncthreads();
  float e0 = expf(row[threadIdx.x]      - mx);
  float e1 = expf(row[threadIdx.x+256]  - mx);
  red[threadIdx.x] = e0 + e1; __syncthreads();
  for (int s=128; s>0; s>>=1) { if (threadIdx.x < s) red[threadIdx.x] += red[threadIdx.x+s]; __syncthreads(); }
  float inv = 1.f/red[0];
  adp[(size_t)i*Nn + threadIdx.x]       = e0*inv;
  adp[(size_t)i*Nn + threadIdx.x + 256] = e1*inv;
}

// ---------------- input transform: x = conv1x1(input[[0,3,5,6]]) -> (B,T,C,N) ----------------
__global__ void k_intransform(const float* __restrict__ input, const float* __restrict__ skw,
                              const float* __restrict__ skb, float* __restrict__ x) {
  size_t idx = (size_t)blockIdx.x*256 + threadIdx.x;
  if (idx >= BTN) return;
  int n = idx & 511;
  size_t bt = idx >> 9;
  int b = (int)(bt / Tt), t = (int)(bt % Tt);
  size_t chs = (size_t)Tt*Nn;
  size_t base = (((size_t)b*7)*Tt + t)*Nn + n;
  float v0 = input[base + 0*chs];
  float v3 = input[base + 3*chs];
  float v5 = input[base + 5*chs];
  float v6 = input[base + 6*chs];
  float* xp = x + bt*Cc*Nn + n;
  #pragma unroll
  for (int c=0;c<32;c++)
    xp[(size_t)c*Nn] = skb[c] + skw[c*4+0]*v0 + skw[c*4+1]*v3 + skw[c*4+2]*v5 + skw[c*4+3]*v6;
}

// ---------------- fused filter/gate conv1x2 -> xg_q ; gout_q = W0@xg + bias (chunk-local) ----------------
__launch_bounds__(256)
__global__ void k_fgconv(const float* __restrict__ x, const float* __restrict__ fw,
                         const float* __restrict__ fb, const float* __restrict__ gw,
                         const float* __restrict__ gb, const float* __restrict__ gcwl,
                         const float* __restrict__ gcb,
                         float* __restrict__ xg, float* __restrict__ gout, int chunk) {
  __shared__ float sfw[2048], sgw[2048], sw0[1024], sfb[32], sgb[32], sgcb[32];
  for (int l = threadIdx.x; l < 2048; l += 256) { sfw[l] = fw[l]; sgw[l] = gw[l]; }
  for (int l = threadIdx.x; l < 1024; l += 256) sw0[l] = gcwl[(l>>5)*224 + (l&31)];
  if (threadIdx.x < 32) {
    sfb[threadIdx.x] = fb[threadIdx.x];
    sgb[threadIdx.x] = gb[threadIdx.x];
    sgcb[threadIdx.x] = gcb[threadIdx.x];
  }
  __syncthreads();
  size_t idx = (size_t)blockIdx.x*256 + threadIdx.x;
  if (idx >= BTNc) return;
  int n = idx & 511;
  size_t btl = idx >> 9;
  int t = (int)(btl % Tt);
  size_t btg = (size_t)chunk*BTc + btl;
  const float* xp = x + btg*Cc*Nn + n;
  float xl[32], xr[32];
  #pragma unroll
  for (int c=0;c<32;c++) xr[c] = xp[(size_t)c*Nn];
  if (t == 0) {
    #pragma unroll
    for (int c=0;c<32;c++) xl[c] = 0.f;
  } else {
    const float* xq = xp - (size_t)Cc*Nn;
    #pragma unroll
    for (int c=0;c<32;c++) xl[c] = xq[(size_t)c*Nn];
  }
  float xgv[32];
  for (int c=0;c<32;c++) {
    float f = sfb[c], g = sgb[c];
    #pragma unroll
    for (int cp=0;cp<32;cp++) {
      f += xl[cp]*sfw[(c*32+cp)*2] + xr[cp]*sfw[(c*32+cp)*2+1];
      g += xl[cp]*sgw[(c*32+cp)*2] + xr[cp]*sgw[(c*32+cp)*2+1];
    }
    xgv[c] = tanhf(f) * sigm(g);
  }
  float* xgp = xg + btl*Cc*Nn + n;
  #pragma unroll
  for (int c=0;c<32;c++) xgp[(size_t)c*Nn] = xgv[c];
  float* gp = gout + btl*Cc*Nn + n;
  for (int o=0;o<32;o++) {
    float s = sgcb[o];
    #pragma unroll
    for (int c=0;c<32;c++) s += sw0[o*32+c]*xgv[c];
    gp[(size_t)o*Nn] = s;
  }
}

// ---------------- support GEMM (per bt: (32x512)@(512x512)) + gconv-slot epilogue ----------------
__launch_bounds__(256)
__global__ void k_supgemm(const float* __restrict__ X, const float* __restrict__ A,
                          const float* __restrict__ gcw, int pslot,
                          float* __restrict__ Y, float* __restrict__ gout, int storeY) {
  __shared__ float sX[32][33];
  __shared__ float sA[32][128];
  __shared__ float sW[1024];
  int tid = threadIdx.x;
  int bt = blockIdx.x >> 2;
  int n0 = (blockIdx.x & 3) << 7;
  const float* Xp = X + (size_t)bt*Cc*Nn;
  for (int l = tid; l < 1024; l += 256)
    sW[l] = gcw[(l>>5)*224 + pslot*32 + (l&31)];
  int tx = tid & 31, ty = tid >> 5;
  float acc[4][4];
  #pragma unroll
  for (int i=0;i<4;i++) { acc[i][0]=0.f; acc[i][1]=0.f; acc[i][2]=0.f; acc[i][3]=0.f; }
  for (int k0 = 0; k0 < Nn; k0 += 32) {
    {
      int r = tid >> 3, kk = (tid & 7) << 2;
      const float4 v = *reinterpret_cast<const float4*>(Xp + (size_t)r*Nn + k0 + kk);
      sX[r][kk] = v.x; sX[r][kk+1] = v.y; sX[r][kk+2] = v.z; sX[r][kk+3] = v.w;
    }
    #pragma unroll
    for (int i=0;i<4;i++) {
      int l = tid + i*256;
      int r = l >> 5, cg_ = l & 31;
      *reinterpret_cast<float4*>(&sA[r][cg_<<2]) =
        *reinterpret_cast<const float4*>(A + (size_t)(k0+r)*Nn + n0 + (cg_<<2));
    }
    __syncthreads();
    #pragma unroll
    for (int k=0;k<32;k++) {
      float4 bv = *reinterpret_cast<const float4*>(&sA[k][tx<<2]);
      float a0 = sX[(ty<<2)+0][k];
      float a1 = sX[(ty<<2)+1][k];
      float a2 = sX[(ty<<2)+2][k];
      float a3 = sX[(ty<<2)+3][k];
      acc[0][0]+=a0*bv.x; acc[0][1]+=a0*bv.y; acc[0][2]+=a0*bv.z; acc[0][3]+=a0*bv.w;
      acc[1][0]+=a1*bv.x; acc[1][1]+=a1*bv.y; acc[1][2]+=a1*bv.z; acc[1][3]+=a1*bv.w;
      acc[2][0]+=a2*bv.x; acc[2][1]+=a2*bv.y; acc[2][2]+=a2*bv.z; acc[2][3]+=a2*bv.w;
      acc[3][0]+=a3*bv.x; acc[3][1]+=a3*bv.y; acc[3][2]+=a3*bv.z; acc[3][3]+=a3*bv.w;
    }
    __syncthreads();
  }
  if (storeY) {
    float* Yp = Y + (size_t)bt*Cc*Nn + n0 + (tx<<2);
    #pragma unroll
    for (int i=0;i<4;i++)
      *reinterpret_cast<float4*>(Yp + (size_t)((ty<<2)+i)*Nn) =
        make_float4(acc[i][0],acc[i][1],acc[i][2],acc[i][3]);
  }
  #pragma unroll
  for (int i=0;i<4;i++)
    *reinterpret_cast<float4*>(&sA[(ty<<2)+i][tx<<2]) =
      make_float4(acc[i][0],acc[i][1],acc[i][2],acc[i][3]);
  __syncthreads();
  float og[4][4];
  #pragma unroll
  for (int i=0;i<4;i++) { og[i][0]=0.f; og[i][1]=0.f; og[i][2]=0.f; og[i][3]=0.f; }
  #pragma unroll 8
  for (int c=0;c<32;c++) {
    float4 yv = *reinterpret_cast<const float4*>(&sA[c][tx<<2]);
    float w0 = sW[((ty<<2)+0)*32 + c];
    float w1 = sW[((ty<<2)+1)*32 + c];
    float w2 = sW[((ty<<2)+2)*32 + c];
    float w3 = sW[((ty<<2)+3)*32 + c];
    og[0][0]+=w0*yv.x; og[0][1]+=w0*yv.y; og[0][2]+=w0*yv.z; og[0][3]+=w0*yv.w;
    og[1][0]+=w1*yv.x; og[1][1]+=w1*yv.y; og[1][2]+=w1*yv.z; og[1][3]+=w1*yv.w;
    og[2][0]+=w2*yv.x; og[2][1]+=w2*yv.y; og[2][2]+=w2*yv.z; og[2][3]+=w2*yv.w;
    og[3][0]+=w3*yv.x; og[3][1]+=w3*yv.y; og[3][2]+=w3*yv.z; og[3][3]+=w3*yv.w;
  }
  float* gp = gout + (size_t)bt*Cc*Nn + n0 + (tx<<2);
  #pragma unroll
  for (int i=0;i<4;i++) {
    float4 cur = *reinterpret_cast<float4*>(gp + (size_t)((ty<<2)+i)*Nn);
    cur.x += og[i][0]; cur.y += og[i][1]; cur.z += og[i][2]; cur.w += og[i][3];
    *reinterpret_cast<float4*>(gp + (size_t)((ty<<2)+i)*Nn) = cur;
  }
}

// ---------------- skip gather: skipK[b,k,c,t] (+)= xg_q[btl,c,node] ----------------
__global__ void k_skipgather(const float* __restrict__ xg, const int* __restrict__ miss,
                             float* __restrict__ skipK, int chunk, int first) {
  int idx = blockIdx.x*256 + threadIdx.x;
  if (idx >= BPC*Kk*Tt) return;
  int t = idx % Tt;
  int k = (idx / Tt) % Kk;
  int bloc = idx / (Tt*Kk);
  int bg = chunk*BPC + bloc;
  int node = miss[bg*Kk + k];
  const float* xp = xg + (((size_t)bloc*Tt + t)*Cc)*Nn + node;
  float* sp = skipK + (((size_t)bg*Kk + k)*Cc)*Tt + t;
  #pragma unroll
  for (int c=0;c<32;c++) {
    float v = xp[(size_t)c*Nn];
    sp[(size_t)c*Tt] = first ? v : (sp[(size_t)c*Tt] + v);
  }
}

// ---------------- ingru: Xs[t,b,n] = sum_c gout_q*iw + ib ----------------
__global__ void k_ingru(const float* __restrict__ gout, const float* __restrict__ iw,
                        const float* __restrict__ ib2, float* __restrict__ Xs, int chunk) {
  size_t idx = (size_t)blockIdx.x*256 + threadIdx.x;
  if (idx >= BTNc) return;
  int n = idx & 511;
  size_t btl = idx >> 9;
  int b = chunk*BPC + (int)(btl / Tt), t = (int)(btl % Tt);
  const float* gp = gout + btl*Cc*Nn + n;
  float s = ib2[0];
  #pragma unroll
  for (int c=0;c<Cc;c++) s += iw[c]*gp[(size_t)c*Nn];
  Xs[((size_t)t*Bb + b)*Nn + n] = s;
}

// ---------------- x += gout_q (chunk fold) ----------------
__global__ void k_xfold(float* __restrict__ x, const float* __restrict__ gout, int chunk) {
  size_t idx = (size_t)blockIdx.x*256 + threadIdx.x;
  if (idx >= BTCNc) return;
  x[(size_t)chunk*BTCNc + idx] += gout[idx];
}

// ---------------- GRU v3: 64 blocks (8 slices x 8 batches), fence-free sync ----------------
// Data plane: SYSTEM-scope cache-bypassing loads/stores (coherence point), so no L2
// writeback/invalidate is ever needed. Weights stay L2-resident (slice = bid%8 -> one
// XCD per slice under round-robin placement; correctness does not depend on placement).
__launch_bounds__(512)
__global__ void k_gru3(const float* __restrict__ Xs, const float* __restrict__ input,
                       const float* __restrict__ zT, const float* __restrict__ rT,
                       const float* __restrict__ hxT, const float* __restrict__ hhT,
                       const float* __restrict__ zb, const float* __restrict__ rb,
                       const float* __restrict__ hb,
                       float* __restrict__ h_g, float* __restrict__ xin_g,
                       float* __restrict__ rh_g, float* __restrict__ outs,
                       int* __restrict__ cnt) {
  __shared__ float xh[1024];     // [ xin(0:512) | h(512:1024) ] for this batch
  __shared__ float rhl[512];
  const int tid = threadIdx.x;
  const int s   = blockIdx.x & 7;     // n-slice (maps to XCD under round-robin)
  const int b   = blockIdx.x >> 3;    // batch
  const int p   = tid >> 4;           // col-pair 0..31
  const int q   = tid & 15;           // K 16-way split
  const int n   = s*64 + p*2;
  int* mycnt = cnt + b*64;
  int bar = 1;

#define GBAR() do { \
    asm volatile("s_waitcnt vmcnt(0)" ::: "memory"); \
    __syncthreads(); \
    if (tid == 0) { \
      atomicAdd(mycnt, 1); \
      while (__hip_atomic_load(mycnt, __ATOMIC_RELAXED, __HIP_MEMORY_SCOPE_SYSTEM) < bar*GRU_P) \
        __builtin_amdgcn_s_sleep(8); \
    } \
    __syncthreads(); \
    bar++; \
  } while (0)

  // t=0 init for own cols: h=0, xin=sigm(Xs0*M0)
  if (tid < 64) {
    int nn = s*64 + tid;
    float Xi = Xs[(size_t)b*Nn + nn];
    float Mi = input[(((size_t)b*7+1)*Tt + 0)*Nn + nn];
    sysstore(h_g + b*Nn + nn, 0.f);
    sysstore(xin_g + b*Nn + nn, sigm(Xi*Mi));
  }
  GBAR();

  const float* Wz = zT  + n;
  const float* Wr = rT  + n;
  const float* Wx = hxT + n;
  const float* Wh = hhT + n;
  const float zbv0 = zb[n], zbv1 = zb[n+1];
  const float rbv0 = rb[n], rbv1 = rb[n+1];
  const float hbv0 = hb[n], hbv1 = hb[n+1];

  float z0=0.f, z1=0.f, hx0=0.f, hx1=0.f, h0v=0.f, h1v=0.f;

  for (int t = 0; t < Tt; t++) {
    // stage xin,h -> LDS (system loads: fresh from coherence point)
    xh[tid]       = sysload(xin_g + b*Nn + tid);
    xh[512 + tid] = sysload(h_g   + b*Nn + tid);
    __syncthreads();
    // ---- phase A: z, r (K=1024), hx (K=512) ----
    float az0=0,az1=0,ar0=0,ar1=0;
    #pragma unroll 4
    for (int i=0;i<64;i++) {
      int j = (i<<4) + q;
      float xv = xh[j];
      float2 wz = *reinterpret_cast<const float2*>(Wz + (size_t)j*Nn);
      float2 wr = *reinterpret_cast<const float2*>(Wr + (size_t)j*Nn);
      az0 += xv*wz.x; az1 += xv*wz.y;
      ar0 += xv*wr.x; ar1 += xv*wr.y;
    }
    float ah0=0, ah1=0;
    #pragma unroll 4
    for (int i=0;i<32;i++) {
      int j = (i<<4) + q;
      float xv = xh[j];
      float2 wx = *reinterpret_cast<const float2*>(Wx + (size_t)j*Nn);
      ah0 += xv*wx.x; ah1 += xv*wx.y;
    }
    #pragma unroll
    for (int d=1; d<16; d<<=1) {
      az0 += __shfl_xor(az0, d); az1 += __shfl_xor(az1, d);
      ar0 += __shfl_xor(ar0, d); ar1 += __shfl_xor(ar1, d);
      ah0 += __shfl_xor(ah0, d); ah1 += __shfl_xor(ah1, d);
    }
    if (q == 0) {
      z0 = sigm(az0 + zbv0); z1 = sigm(az1 + zbv1);
      hx0 = ah0; hx1 = ah1;
      h0v = xh[512+n]; h1v = xh[512+n+1];
      float r0 = sigm(ar0 + rbv0), r1 = sigm(ar1 + rbv1);
      sysstore(rh_g + b*Nn + n,     r0*h0v);
      sysstore(rh_g + b*Nn + n + 1, r1*h1v);
    }
    GBAR();
    // stage rh -> LDS
    rhl[tid] = sysload(rh_g + b*Nn + tid);
    __syncthreads();
    // ---- phase B: hh (K=512) + combine ----
    float hh0=0, hh1=0;
    #pragma unroll 4
    for (int i=0;i<32;i++) {
      int m = (i<<4) + q;
      float rv = rhl[m];
      float2 wh = *reinterpret_cast<const float2*>(Wh + (size_t)m*Nn);
      hh0 += rv*wh.x; hh1 += rv*wh.y;
    }
    #pragma unroll
    for (int d=1; d<16; d<<=1) { hh0 += __shfl_xor(hh0,d); hh1 += __shfl_xor(hh1,d); }
    if (q == 0) {
      float ht0 = tanhf(hx0 + hh0 + hbv0);
      float ht1 = tanhf(hx1 + hh1 + hbv1);
      float hn0 = (1.f - z0)*h0v + z0*ht0;
      float hn1 = (1.f - z1)*h1v + z1*ht1;
      *reinterpret_cast<float2*>(outs + ((size_t)t*Bb + b)*Nn + n) = make_float2(hn0, hn1);
      sysstore(h_g + b*Nn + n,     hn0);
      sysstore(h_g + b*Nn + n + 1, hn1);
      if (t+1 < Tt) {
        float Xi0 = Xs[((size_t)(t+1)*Bb + b)*Nn + n];
        float Xi1 = Xs[((size_t)(t+1)*Bb + b)*Nn + n + 1];
        float Mi0 = input[(((size_t)b*7+1)*Tt + (t+1))*Nn + n];
        float Mi1 = input[(((size_t)b*7+1)*Tt + (t+1))*Nn + n + 1];
        sysstore(xin_g + b*Nn + n,     sigm(Xi0*Mi0 + hn0*(1.f - Mi0)));
        sysstore(xin_g + b*Nn + n + 1, sigm(Xi1*Mi1 + hn1*(1.f - Mi1)));
      }
    }
    GBAR();
  }
#undef GBAR
}

// ---------------- x += outs*rw + rb (after GRU) ----------------
__global__ void k_xre(float* __restrict__ x, const float* __restrict__ outs,
                      const float* __restrict__ rw, const float* __restrict__ rb2) {
  size_t idx = (size_t)blockIdx.x*256 + threadIdx.x;
  if (idx >= BTCN) return;
  int n = idx & 511;
  int c = (int)((idx >> 9) & 31);
  size_t bt = idx >> 14;
  int b = (int)(bt / Tt), t = (int)(bt % Tt);
  float o = outs[((size_t)t*Bb + b)*Nn + n];
  x[idx] += o*rw[c] + rb2[c];
}

// ---------------- head: relu(skipK) -> end1 relu -> end2 ----------------
__launch_bounds__(256)
__global__ void k_head(const float* __restrict__ skipK,
                       const float* __restrict__ e1w, const float* __restrict__ e1b,
                       const float* __restrict__ e2w, const float* __restrict__ e2b,
                       float* __restrict__ out) {
  __shared__ float sw[2048], sb[64], s2[64];
  for (int l = threadIdx.x; l < 2048; l += 256) sw[l] = e1w[l];
  if (threadIdx.x < 64) { sb[threadIdx.x] = e1b[threadIdx.x]; s2[threadIdx.x] = e2w[threadIdx.x]; }
  __syncthreads();
  int idx = blockIdx.x*256 + threadIdx.x;
  if (idx >= Bb*Kk*Tt) return;
  int t = idx % Tt;
  int k = (idx / Tt) % Kk;
  int b = idx / (Tt*Kk);
  const float* sp = skipK + (((size_t)b*Kk + k)*Cc)*Tt + t;
  float in[32];
  #pragma unroll
  for (int c=0;c<32;c++) in[c] = fmaxf(sp[(size_t)c*Tt], 0.f);
  float acc = e2b[0];
  for (int o=0;o<64;o++) {
    float s = sb[o];
    #pragma unroll
    for (int c=0;c<32;c++) s += sw[o*32+c]*in[c];
    acc += s2[o]*fmaxf(s, 0.f);
  }
  out[idx] = acc;
}

extern "C" void kernel_launch(void* const* d_in, const int* in_sizes, int n_in,
                              void* d_out, int out_size, void* d_ws, size_t ws_size,
                              hipStream_t stream) {
  const float* input = (const float*)d_in[0];
  const int*   miss  = (const int*)  d_in[1];
  const float* sup0  = (const float*)d_in[2];
  const float* sup1  = (const float*)d_in[3];
  const float* nv1   = (const float*)d_in[4];
  const float* nv2   = (const float*)d_in[5];
  const float* skw   = (const float*)d_in[6];
  const float* skb   = (const float*)d_in[7];
  const float* fw    = (const float*)d_in[8];
  const float* fb    = (const float*)d_in[9];
  const float* gw    = (const float*)d_in[10];
  const float* gb    = (const float*)d_in[11];
  const float* gcw   = (const float*)d_in[12];
  const float* gcb   = (const float*)d_in[13];
  const float* iw    = (const float*)d_in[14];
  const float* ib2   = (const float*)d_in[15];
  const float* rw    = (const float*)d_in[16];
  const float* rb2   = (const float*)d_in[17];
  const float* zl    = (const float*)d_in[18];
  const float* zb    = (const float*)d_in[19];
  const float* rl    = (const float*)d_in[20];
  const float* rb    = (const float*)d_in[21];
  const float* hl    = (const float*)d_in[22];
  const float* hb    = (const float*)d_in[23];
  const float* e1w   = (const float*)d_in[24];
  const float* e1b   = (const float*)d_in[25];
  const float* e2w   = (const float*)d_in[26];
  const float* e2b   = (const float*)d_in[27];
  float* out = (float*)d_out;

  float* p     = (float*)d_ws;
  float* x     = p; p += BTCN;
  float* xg    = p; p += BTCNc;
  float* tmp1  = p; p += BTCNc;
  float* gout  = p; p += BTCNc;
  float* skipK = p; p += (size_t)Bb*Kk*Cc*Tt;
  float* adp   = p; p += (size_t)Nn*Nn;
  float* zT    = p; p += (size_t)1024*Nn;
  float* rT    = p; p += (size_t)1024*Nn;
  float* hxT   = p; p += (size_t)Nn*Nn;
  float* hhT   = p; p += (size_t)Nn*Nn;
  float* Xs    = p; p += (size_t)Tt*Bb*Nn;
  float* outs  = p; p += (size_t)Tt*Bb*Nn;
  float* h_g   = p; p += Bb*Nn;
  float* xin_g = p; p += Bb*Nn;
  float* rh_g  = p; p += Bb*Nn;
  int*   cnt   = (int*)p; p += Bb*64;

  k_wt<<<(Nn*1024 + 255)/256, 256, 0, stream>>>(zl, rl, hl, zT, rT, hxT, hhT);
  k_adp<<<Nn, 256, 0, stream>>>(nv1, nv2, adp);
  k_intransform<<<(int)((BTN + 255)/256), 256, 0, stream>>>(input, skw, skb, x);

  const float* sups[3] = {sup0, sup1, adp};
  for (int layer = 0; layer < Ll; layer++) {
    for (int chunk = 0; chunk < NCH; chunk++) {
      k_fgconv<<<(int)((BTNc + 255)/256), 256, 0, stream>>>(
          x, fw + layer*2048, fb + layer*32, gw + layer*2048, gb + layer*32,
          gcw + layer*32*224, gcb + layer*32, xg, gout, chunk);
      for (int s = 0; s < 3; s++) {
        k_supgemm<<<BTc*4, 256, 0, stream>>>(xg,   sups[s], gcw + layer*32*224, 2*s+1, tmp1, gout, 1);
        k_supgemm<<<BTc*4, 256, 0, stream>>>(tmp1, sups[s], gcw + layer*32*224, 2*s+2, tmp1, gout, 0);
      }
      k_skipgather<<<(BPC*Kk*Tt + 255)/256, 256, 0, stream>>>(xg, miss, skipK, chunk, layer == 0 ? 1 : 0);
      k_ingru<<<(int)((BTNc + 255)/256), 256, 0, stream>>>(gout, iw, ib2, Xs, chunk);
      k_xfold<<<(int)((BTCNc + 255)/256), 256, 0, stream>>>(x, gout, chunk);
    }
    hipMemsetAsync(cnt, 0, Bb*64*sizeof(int), stream);
    k_gru3<<<dim3(Bb*GRU_P), dim3(512), 0, stream>>>(
        Xs, input, zT, rT, hxT, hhT, zb, rb, hb, h_g, xin_g, rh_g, outs, cnt);
    k_xre<<<(int)((BTCN + 255)/256), 256, 0, stream>>>(x, outs, rw, rb2);
  }
  k_head<<<(Bb*Kk*Tt + 255)/256, 256, 0, stream>>>(skipK, e1w, e1b, e2w, e2b, out);
}